// Round 1
// baseline (689.701 us; speedup 1.0000x reference)
//
#include <hip/hip_runtime.h>

// WaveCell: 2D staggered-grid elastic FDTD timestep, fused single kernel.
// B=4, NZ=NX=2048, fp32. Periodic wrap via & (pow2 dims).
// Stress update needs NEW velocities at (z,x),(z,x+1),(z+1,x) [vx] and
// (z,x),(z-1,x),(z,x-1) [vz] -> recompute redundantly per point (cache-served).

constexpr int NZ = 2048;
constexpr int NX = 2048;
constexpr int B  = 4;
constexpr int PLANE = NZ * NX;      // 4,194,304
constexpr int VOL   = B * PLANE;    // 16,777,216
constexpr float DT    = 1e-3f;
constexpr float INV_H = 0.1f;       // 1/10m

__device__ __forceinline__ float rcpf(float x) { return __builtin_amdgcn_rcpf(x); }

// vx_new(z,x) = a*vx + b*((txx[z,x]-txx[z,x-1]) + (txz[z,x]-txz[z-1,x]))/(H*rho)
__device__ __forceinline__ float vx_new_at(
    const float* __restrict__ txx, const float* __restrict__ txz,
    const float* __restrict__ vx,  const float* __restrict__ rho,
    const float* __restrict__ dd, int b3, int z, int x)
{
    const int zm = (z - 1) & (NZ - 1);
    const int xm = (x - 1) & (NX - 1);
    const int i2 = z * NX + x;
    const int i3 = b3 + i2;
    const float c   = 0.5f * DT * dd[i2];
    const float inv = rcpf(1.0f + c);
    const float a   = (1.0f - c) * inv;
    const float bb  = DT * inv;
    const float rhs = (txx[i3] - txx[b3 + z * NX + xm])
                    + (txz[i3] - txz[b3 + zm * NX + x]);
    return a * vx[i3] + bb * rhs * INV_H * rcpf(rho[i2]);
}

// vz_new(z,x) = a*vz + b*((txz[z,x+1]-txz[z,x]) + (tzz[z+1,x]-tzz[z,x]))/(H*rho)
__device__ __forceinline__ float vz_new_at(
    const float* __restrict__ tzz, const float* __restrict__ txz,
    const float* __restrict__ vz,  const float* __restrict__ rho,
    const float* __restrict__ dd, int b3, int z, int x)
{
    const int zp = (z + 1) & (NZ - 1);
    const int xp = (x + 1) & (NX - 1);
    const int i2 = z * NX + x;
    const int i3 = b3 + i2;
    const float c   = 0.5f * DT * dd[i2];
    const float inv = rcpf(1.0f + c);
    const float a   = (1.0f - c) * inv;
    const float bb  = DT * inv;
    const float rhs = (txz[b3 + z * NX + xp] - txz[i3])
                    + (tzz[b3 + zp * NX + x] - tzz[i3]);
    return a * vz[i3] + bb * rhs * INV_H * rcpf(rho[i2]);
}

__global__ __launch_bounds__(256) void wave_fused(
    const float* __restrict__ vp,  const float* __restrict__ vs,
    const float* __restrict__ rho,
    const float* __restrict__ vx,  const float* __restrict__ vz,
    const float* __restrict__ txx, const float* __restrict__ tzz,
    const float* __restrict__ txz,
    const float* __restrict__ dd,
    float* __restrict__ out)
{
    const int i = blockIdx.x * blockDim.x + threadIdx.x;
    if (i >= VOL) return;
    const int x  = i & (NX - 1);
    const int z  = (i >> 11) & (NZ - 1);
    const int b  = i >> 22;
    const int b3 = b * PLANE;
    const int zm = (z - 1) & (NZ - 1);
    const int zp = (z + 1) & (NZ - 1);
    const int xm = (x - 1) & (NX - 1);
    const int xp = (x + 1) & (NX - 1);

    // new velocities at the 6 needed staggered locations
    const float vxn_c  = vx_new_at(txx, txz, vx, rho, dd, b3, z,  x);
    const float vxn_xp = vx_new_at(txx, txz, vx, rho, dd, b3, z,  xp);
    const float vxn_zp = vx_new_at(txx, txz, vx, rho, dd, b3, zp, x);
    const float vzn_c  = vz_new_at(tzz, txz, vz, rho, dd, b3, z,  x);
    const float vzn_zm = vz_new_at(tzz, txz, vz, rho, dd, b3, zm, x);
    const float vzn_xm = vz_new_at(tzz, txz, vz, rho, dd, b3, z,  xm);

    const int i2 = z * NX + x;
    const int i3 = b3 + i2;
    const float rh  = rho[i2];
    const float vpv = vp[i2];
    const float vsv = vs[i2];
    const float mu  = rh * vsv * vsv;
    const float lam = rh * vpv * vpv - 2.0f * mu;
    const float lam2mu = lam + 2.0f * mu;
    const float c   = 0.5f * DT * dd[i2];
    const float inv = rcpf(1.0f + c);
    const float a   = (1.0f - c) * inv;
    const float bb  = DT * inv;

    const float vx_x = (vxn_xp - vxn_c) * INV_H;
    const float vz_z = (vzn_c - vzn_zm) * INV_H;
    const float txxn = a * txx[i3] + bb * (lam2mu * vx_x + lam * vz_z);
    const float tzzn = a * tzz[i3] + bb * (lam2mu * vz_z + lam * vx_x);
    const float txzn = a * txz[i3] + bb * mu
                     * ((vxn_zp - vxn_c) * INV_H + (vzn_c - vzn_xm) * INV_H);

    out[0 * VOL + i3] = vxn_c;
    out[1 * VOL + i3] = vzn_c;
    out[2 * VOL + i3] = txxn;
    out[3 * VOL + i3] = tzzn;
    out[4 * VOL + i3] = txzn;
}

extern "C" void kernel_launch(void* const* d_in, const int* in_sizes, int n_in,
                              void* d_out, int out_size, void* d_ws, size_t ws_size,
                              hipStream_t stream) {
    const float* vp  = (const float*)d_in[0];
    const float* vs  = (const float*)d_in[1];
    const float* rho = (const float*)d_in[2];
    const float* vx  = (const float*)d_in[3];
    const float* vz  = (const float*)d_in[4];
    const float* txx = (const float*)d_in[5];
    const float* tzz = (const float*)d_in[6];
    const float* txz = (const float*)d_in[7];
    const float* dd  = (const float*)d_in[8];
    float* out = (float*)d_out;

    const int threads = 256;
    const int blocks  = VOL / threads;  // 65536, exact
    hipLaunchKernelGGL(wave_fused, dim3(blocks), dim3(threads), 0, stream,
                       vp, vs, rho, vx, vz, txx, tzz, txz, dd, out);
}